// Round 1
// 229.409 us; speedup vs baseline: 1.1291x; 1.1291x over previous
//
#include <hip/hip_runtime.h>
#include <hip/hip_bf16.h>
#include <math.h>

#define EPSF 1e-12f

typedef __attribute__((ext_vector_type(8))) short bf16x8;
typedef __attribute__((ext_vector_type(4))) float f32x4;
typedef __attribute__((ext_vector_type(4))) short short4v;
typedef __attribute__((ext_vector_type(4))) unsigned short ushort4v;

static __device__ __forceinline__ short f2bf(float f) {
  union { __hip_bfloat16 h; short s; } u;
  u.h = __float2bfloat16(f);
  return u.s;
}

// K2: logits = (w @ x) * invn[s]  via bf16 MFMA; fused per-s L2-norm;
// softmax over k; writes a' = a*invn (bf16) and suma (fp32 atomics).
// Block: one (n, 64-s tile). 4 waves, wave w owns k-rows [16w,16w+16).
// xf pitch 70: gather bank = (70*(cb+j)+col)%32 = (6(cb+j)+col)%32; the 8 j's
// hit 8 distinct banks and quads alias only 2-way (free, m136).
// NOTE (R4 post-mortem): replacing this gather with an in-LDS transpose
// regressed k2 35->92 us (3rd barrier/tile + 8-way-conflicted transpose
// reads + scalar b16 writes serialize at ~2 blocks/CU). Keep the gather.
// NOTE (R5): left untouched — adding A/B prefetch regs here risks VGPR>128
// which would halve the 4-blocks/CU co-residency.
__global__ __launch_bounds__(256) void k2_mfma(
    const float* __restrict__ x, const float* __restrict__ w,
    unsigned short* __restrict__ ap, float* __restrict__ suma) {
  __shared__ __align__(16) float xf[64][70];   // [c_local][s_local] fp32
  __shared__ __align__(16) short wb[64][72];   // [k][c_local] bf16
  __shared__ __align__(16) float red[4][64];   // per-wave reduction scratch
  __shared__ float invs[64];
  __shared__ float gmaxs[64];
  __shared__ float gsums[64];

  const int n = blockIdx.y;
  const int s0 = blockIdx.x << 6;
  const int t = threadIdx.x;
  const int lane = t & 63;
  const int wid = t >> 6;        // wave id = k-band
  const int col = t & 15;        // MFMA col (s) / frag row
  const int quad = (t >> 4) & 3; // MFMA quad
  const int cr = t >> 4;         // staging row 0..15
  const int sg = t & 15;         // staging float4 col

  f32x4 acc[4] = {{0,0,0,0},{0,0,0,0},{0,0,0,0},{0,0,0,0}};
  float ssq0 = 0.f, ssq1 = 0.f, ssq2 = 0.f, ssq3 = 0.f;

  for (int c0 = 0; c0 < 512; c0 += 64) {
#pragma unroll
    for (int p = 0; p < 4; ++p) {
      int c = cr + (p << 4);
      float4 g = *(const float4*)&x[((size_t)((n << 9) + c0 + c) << 10) + s0 + (sg << 2)];
      float2 glo; glo.x = g.x; glo.y = g.y;
      float2 ghi; ghi.x = g.z; ghi.y = g.w;
      *(float2*)&xf[c][sg << 2] = glo;
      *(float2*)&xf[c][(sg << 2) + 2] = ghi;
      ssq0 = fmaf(g.x, g.x, ssq0); ssq1 = fmaf(g.y, g.y, ssq1);
      ssq2 = fmaf(g.z, g.z, ssq2); ssq3 = fmaf(g.w, g.w, ssq3);
      float4 gw = *(const float4*)&w[(c << 9) + c0 + (sg << 2)];  // w[k=c][c0+4sg]
      short4v hw; hw.x = f2bf(gw.x); hw.y = f2bf(gw.y); hw.z = f2bf(gw.z); hw.w = f2bf(gw.w);
      *(short4v*)&wb[c][sg << 2] = hw;
    }
    __syncthreads();
#pragma unroll
    for (int cc = 0; cc < 64; cc += 32) {
      bf16x8 af = *(const bf16x8*)&wb[(wid << 4) + col][cc + (quad << 3)];
      int cb = cc + (quad << 3);
#pragma unroll
      for (int sgr = 0; sgr < 4; ++sgr) {
        int sc = (sgr << 4) + col;
        bf16x8 bfr;
#pragma unroll
        for (int j = 0; j < 8; ++j) bfr[j] = f2bf(xf[cb + j][sc]);  // 2-way (free)
        acc[sgr] = __builtin_amdgcn_mfma_f32_16x16x32_bf16(af, bfr, acc[sgr], 0, 0, 0);
      }
    }
    __syncthreads();
  }

  // ---- per-s inverse norm (thread's 4 s fixed = 4sg..4sg+3) ----
  ssq0 += __shfl_xor(ssq0, 16, 64); ssq0 += __shfl_xor(ssq0, 32, 64);
  ssq1 += __shfl_xor(ssq1, 16, 64); ssq1 += __shfl_xor(ssq1, 32, 64);
  ssq2 += __shfl_xor(ssq2, 16, 64); ssq2 += __shfl_xor(ssq2, 32, 64);
  ssq3 += __shfl_xor(ssq3, 16, 64); ssq3 += __shfl_xor(ssq3, 32, 64);
  if (lane < 16) {
    float4 v; v.x = ssq0; v.y = ssq1; v.z = ssq2; v.w = ssq3;
    *(float4*)&red[wid][sg << 2] = v;
  }
  __syncthreads();
  if (t < 64) {
    float tot = red[0][t] + red[1][t] + red[2][t] + red[3][t];
    invs[t] = 1.0f / fmaxf(sqrtf(tot), EPSF);
  }
  __syncthreads();

  // ---- softmax over k for each s ----
  float li[4];
#pragma unroll
  for (int sgr = 0; sgr < 4; ++sgr) li[sgr] = invs[(sgr << 4) + col];
  float le[4][4];
#pragma unroll
  for (int sgr = 0; sgr < 4; ++sgr)
#pragma unroll
    for (int r = 0; r < 4; ++r) le[sgr][r] = acc[sgr][r] * li[sgr];

  float mx[4];
#pragma unroll
  for (int sgr = 0; sgr < 4; ++sgr) {
    float m = fmaxf(fmaxf(le[sgr][0], le[sgr][1]), fmaxf(le[sgr][2], le[sgr][3]));
    m = fmaxf(m, __shfl_xor(m, 16, 64));
    m = fmaxf(m, __shfl_xor(m, 32, 64));
    mx[sgr] = m;
  }
  if (lane < 16) {
#pragma unroll
    for (int sgr = 0; sgr < 4; ++sgr) red[wid][(sgr << 4) + sg] = mx[sgr];
  }
  __syncthreads();
  if (t < 64)
    gmaxs[t] = fmaxf(fmaxf(red[0][t], red[1][t]), fmaxf(red[2][t], red[3][t]));
  __syncthreads();

  float ps[4];
#pragma unroll
  for (int sgr = 0; sgr < 4; ++sgr) {
    float gm = gmaxs[(sgr << 4) + col];
    float p = 0.f;
#pragma unroll
    for (int r = 0; r < 4; ++r) {
      float e = __expf(le[sgr][r] - gm);
      le[sgr][r] = e;
      p += e;
    }
    p += __shfl_xor(p, 16, 64);
    p += __shfl_xor(p, 32, 64);
    ps[sgr] = p;
  }
  if (lane < 16) {
#pragma unroll
    for (int sgr = 0; sgr < 4; ++sgr) red[wid][(sgr << 4) + sg] = ps[sgr];
  }
  __syncthreads();
  if (t < 64) gsums[t] = red[0][t] + red[1][t] + red[2][t] + red[3][t];
  __syncthreads();

  // ---- a, a' = a*invn, suma ----
  float sk[4] = {0.f, 0.f, 0.f, 0.f};
#pragma unroll
  for (int sgr = 0; sgr < 4; ++sgr) {
    float rinv = 1.0f / gsums[(sgr << 4) + col];
#pragma unroll
    for (int r = 0; r < 4; ++r) {
      float av = le[sgr][r] * rinv;            // a
      sk[r] += av;
      float apv = av * li[sgr];                // a' = a*invn[s]
      int k = (wid << 4) + (quad << 2) + r;
      ap[((size_t)((n << 6) + k) << 10) + s0 + (sgr << 4) + col] =
          (unsigned short)f2bf(apv);
    }
  }
#pragma unroll
  for (int r = 0; r < 4; ++r) {
    sk[r] += __shfl_xor(sk[r], 1, 64);
    sk[r] += __shfl_xor(sk[r], 2, 64);
    sk[r] += __shfl_xor(sk[r], 4, 64);
    sk[r] += __shfl_xor(sk[r], 8, 64);
  }
  if (col == 0) {
#pragma unroll
    for (int r = 0; r < 4; ++r)
      atomicAdd(&suma[(n << 6) + (wid << 4) + (quad << 2) + r], sk[r]);
  }
}

// K3: vlad^T[c,k] = sum_s x[c,s]*a'[k,s]  (bf16 MFMA, x as A, a' as B),
// then - suma[k]*cent[k,c], rnorm2 atomics, LDS-transposed coalesced store.
// R5 changes:
//  (1) grid transposed to dim3(64,8): linear wg id = n + 64*c0t, so all 8
//      c0-blocks sharing ap[n] (128 KB) are == n (mod 8) -> SAME XCD ->
//      ap is fetched from HBM once per n (8 MB) instead of 8x (64 MB).
//  (2) T14 async-STAGE double-buffer: next tile's global loads (x fp32 +
//      ap bf16) are issued into a second register set right after the
//      barrier that publishes the current tile, and written to LDS only
//      after the current tile's MFMAs + barrier. ~900cy HBM latency hides
//      under MFMA + the other resident block's phases.
#define K3_LOADT(gx, ga, S0)                                                   \
  do {                                                                         \
    _Pragma("unroll") for (int p = 0; p < 4; ++p) {                            \
      gx[p] = *(const float4*)(xbase + ((size_t)(p << 4) << 10) + (S0));       \
      ga[p] = *(const ushort4v*)(abase + ((size_t)(p << 4) << 10) + (S0));     \
    }                                                                          \
  } while (0)

#define K3_WRITET(gx, ga)                                                      \
  do {                                                                         \
    _Pragma("unroll") for (int p = 0; p < 4; ++p) {                            \
      int c = cr + (p << 4);                                                   \
      short4v hx;                                                              \
      hx.x = f2bf(gx[p].x); hx.y = f2bf(gx[p].y);                              \
      hx.z = f2bf(gx[p].z); hx.w = f2bf(gx[p].w);                              \
      *(short4v*)&xb[c][sg << 2] = hx;                                         \
      *(ushort4v*)&at[c][sg << 2] = ga[p];                                     \
    }                                                                          \
  } while (0)

#define K3_MFMAT()                                                             \
  do {                                                                         \
    _Pragma("unroll") for (int ss = 0; ss < 64; ss += 32) {                    \
      bf16x8 af = *(const bf16x8*)&xb[(wid << 4) + col][ss + (quad << 3)];     \
      _Pragma("unroll") for (int kt = 0; kt < 4; ++kt) {                       \
        bf16x8 bfr = *(const bf16x8*)&at[(kt << 4) + col][ss + (quad << 3)];   \
        acc[kt] = __builtin_amdgcn_mfma_f32_16x16x32_bf16(af, bfr, acc[kt], 0, 0, 0); \
      }                                                                        \
    }                                                                          \
  } while (0)

__global__ __launch_bounds__(256) void k3_mfma(
    const float* __restrict__ x, const unsigned short* __restrict__ ap,
    const float* __restrict__ cent, const float* __restrict__ suma,
    float* __restrict__ out, float* __restrict__ rnorm2) {
  __shared__ __align__(16) char sm[64 * 72 * 2 * 2];  // 18432 B
  short (*xb)[72] = reinterpret_cast<short(*)[72]>(sm);          // [c][s] bf16
  short (*at)[72] = reinterpret_cast<short(*)[72]>(sm + 9216);   // [k][s] bf16
  float (*lt)[68] = reinterpret_cast<float(*)[68]>(sm);          // [k][c] (epilogue)

  const int n = blockIdx.x;            // R5: swapped (XCD-local ap, see header)
  const int c0 = blockIdx.y << 6;
  const int t = threadIdx.x;
  const int lane = t & 63;
  const int wid = t >> 6;        // c-band
  const int col = t & 15;
  const int quad = (t >> 4) & 3;
  const int cr = t >> 4;
  const int sg = t & 15;

  f32x4 acc[4] = {{0,0,0,0},{0,0,0,0},{0,0,0,0},{0,0,0,0}};

  const float* xbase = &x[((size_t)((n << 9) + c0 + cr) << 10) + (sg << 2)];
  const unsigned short* abase = &ap[((size_t)((n << 6) + cr) << 10) + (sg << 2)];

  float4 gxA[4]; ushort4v gaA[4];
  float4 gxB[4]; ushort4v gaB[4];

  K3_LOADT(gxA, gaA, 0);
#pragma unroll 1
  for (int it = 0; it < 8; ++it) {
    // ---- tile 2*it (regs A) ----
    K3_WRITET(gxA, gaA);
    __syncthreads();
    K3_LOADT(gxB, gaB, (size_t)(((it << 1) + 1) << 6));  // prefetch tile 2it+1
    K3_MFMAT();
    __syncthreads();
    // ---- tile 2*it+1 (regs B) ----
    K3_WRITET(gxB, gaB);
    __syncthreads();
    if (it < 7) {
      K3_LOADT(gxA, gaA, (size_t)(((it << 1) + 2) << 6));  // prefetch tile 2it+2
    }
    K3_MFMAT();
    __syncthreads();
  }

  // epilogue: lane holds D[c = wid*16+quad*4+r][k = kt*16+col]
  float sa[4];
#pragma unroll
  for (int kt = 0; kt < 4; ++kt) sa[kt] = suma[(n << 6) + (kt << 4) + col];
  const int crow = (wid << 4) + (quad << 2);
  float r2[4] = {0.f, 0.f, 0.f, 0.f};
#pragma unroll
  for (int kt = 0; kt < 4; ++kt) {
    int k = (kt << 4) + col;
#pragma unroll
    for (int r = 0; r < 4; ++r) {
      int c = crow + r;
      float ce = cent[(k << 9) + c0 + c];
      float val = acc[kt][r] - sa[kt] * ce;
      r2[kt] = fmaf(val, val, r2[kt]);
      lt[k][c] = val;
    }
  }
#pragma unroll
  for (int kt = 0; kt < 4; ++kt) {
    r2[kt] += __shfl_xor(r2[kt], 16, 64);
    r2[kt] += __shfl_xor(r2[kt], 32, 64);
  }
  if (lane < 16) {
#pragma unroll
    for (int kt = 0; kt < 4; ++kt)
      atomicAdd(&rnorm2[(n << 6) + (kt << 4) + sg], r2[kt]);
  }
  __syncthreads();
  // coalesced store of the 64k x 64c tile
#pragma unroll
  for (int u = 0; u < 4; ++u) {
    int k = t >> 2;
    int c = ((t & 3) << 2) + (u << 4);
    float4 v = *(const float4*)&lt[k][c];
    *(float4*)&out[((size_t)((n << 6) + k) << 9) + c0 + c] = v;
  }
}

// K5 (R5: absorbs former K4): per block (1024 consecutive floats = one n,
// two k-rows), wave 0 recomputes the per-n global-norm factor from rnorm2
// (64 floats, L2-hot) and broadcasts via LDS; then in-place scale.
// fac[n,k] = (1/max(rn_k,eps)) * 1/max(sqrt(sum_k (rn_k/max(rn_k,eps))^2),eps)
__global__ __launch_bounds__(256) void k5_scale(const float* __restrict__ vlad,
                                                const float* __restrict__ rnorm2,
                                                float* __restrict__ out) {
  __shared__ float gsh;
  const int b = blockIdx.x;
  const int t = threadIdx.x;
  const int n = b >> 5;                 // 32 blocks per n
  if (t < 64) {                          // wave 0 only
    float rn = sqrtf(rnorm2[(n << 6) + t]);
    float nr = rn / fmaxf(rn, EPSF);
    float g = nr * nr;
#pragma unroll
    for (int off = 32; off > 0; off >>= 1) g += __shfl_xor(g, off, 64);
    if (t == 0) gsh = g;
  }
  __syncthreads();
  const float ginv = 1.0f / fmaxf(sqrtf(gsh), EPSF);
  const int idx = (b << 8) + t;          // float4 index
  const int kg = idx >> 7;               // = n*64 + k  (512 floats per k-row)
  float rn = sqrtf(rnorm2[kg]);
  float f = (1.0f / fmaxf(rn, EPSF)) * ginv;
  float4 v = ((const float4*)vlad)[idx];
  float4 o;
  o.x = v.x * f; o.y = v.y * f; o.z = v.z * f; o.w = v.w * f;
  ((float4*)out)[idx] = o;
}

extern "C" void kernel_launch(void* const* d_in, const int* in_sizes, int n_in,
                              void* d_out, int out_size, void* d_ws, size_t ws_size,
                              hipStream_t stream) {
  (void)in_sizes; (void)n_in; (void)out_size; (void)ws_size;
  const float* x = (const float*)d_in[0];     // (64,512,32,32)
  const float* w = (const float*)d_in[1];     // (64,512)
  const float* cent = (const float*)d_in[2];  // (64,512)
  float* out = (float*)d_out;                 // (64, 64*512)

  float* ws = (float*)d_ws;
  float* suma = ws;                                   // 4096
  float* rnorm2 = ws + 4096;                          // 4096
  unsigned short* ap = (unsigned short*)(ws + 12288); // 64*64*1024 bf16 = 8 MB

  hipMemsetAsync(ws, 0, 8192 * sizeof(float), stream);  // suma + rnorm2
  k2_mfma<<<dim3(16, 64), 256, 0, stream>>>(x, w, ap, suma);
  k3_mfma<<<dim3(64, 8), 256, 0, stream>>>(x, ap, cent, suma, out, rnorm2);
  k5_scale<<<2048, 256, 0, stream>>>(out, rnorm2, out);
}

// Round 2
// 228.257 us; speedup vs baseline: 1.1348x; 1.0050x over previous
//
#include <hip/hip_runtime.h>
#include <hip/hip_bf16.h>
#include <math.h>

#define EPSF 1e-12f

typedef __attribute__((ext_vector_type(8))) short bf16x8;
typedef __attribute__((ext_vector_type(4))) float f32x4;
typedef __attribute__((ext_vector_type(4))) short short4v;
typedef __attribute__((ext_vector_type(4))) unsigned short ushort4v;

static __device__ __forceinline__ short f2bf(float f) {
  union { __hip_bfloat16 h; short s; } u;
  u.h = __float2bfloat16(f);
  return u.s;
}

// K2: logits = (w @ x) * invn[s]  via bf16 MFMA; fused per-s L2-norm;
// softmax over k; writes a' = a*invn (bf16) and suma (fp32 atomics).
// Block: one (n, 64-s tile). 4 waves, wave w owns k-rows [16w,16w+16).
// xf pitch 70: gather bank = (70*(cb+j)+col)%32 = (6(cb+j)+col)%32; the 8 j's
// hit 8 distinct banks and quads alias only 2-way (free, m136).
// NOTE (R4 post-mortem): replacing this gather with an in-LDS transpose
// regressed k2 35->92 us (3rd barrier/tile + 8-way-conflicted transpose
// reads + scalar b16 writes serialize at ~2 blocks/CU). Keep the gather.
// NOTE (R5): left untouched — adding A/B prefetch regs here risks VGPR>128
// which would halve the 4-blocks/CU co-residency.
__global__ __launch_bounds__(256) void k2_mfma(
    const float* __restrict__ x, const float* __restrict__ w,
    unsigned short* __restrict__ ap, float* __restrict__ suma) {
  __shared__ __align__(16) float xf[64][70];   // [c_local][s_local] fp32
  __shared__ __align__(16) short wb[64][72];   // [k][c_local] bf16
  __shared__ __align__(16) float red[4][64];   // per-wave reduction scratch
  __shared__ float invs[64];
  __shared__ float gmaxs[64];
  __shared__ float gsums[64];

  const int n = blockIdx.y;
  const int s0 = blockIdx.x << 6;
  const int t = threadIdx.x;
  const int lane = t & 63;
  const int wid = t >> 6;        // wave id = k-band
  const int col = t & 15;        // MFMA col (s) / frag row
  const int quad = (t >> 4) & 3; // MFMA quad
  const int cr = t >> 4;         // staging row 0..15
  const int sg = t & 15;         // staging float4 col

  f32x4 acc[4] = {{0,0,0,0},{0,0,0,0},{0,0,0,0},{0,0,0,0}};
  float ssq0 = 0.f, ssq1 = 0.f, ssq2 = 0.f, ssq3 = 0.f;

  for (int c0 = 0; c0 < 512; c0 += 64) {
#pragma unroll
    for (int p = 0; p < 4; ++p) {
      int c = cr + (p << 4);
      float4 g = *(const float4*)&x[((size_t)((n << 9) + c0 + c) << 10) + s0 + (sg << 2)];
      float2 glo; glo.x = g.x; glo.y = g.y;
      float2 ghi; ghi.x = g.z; ghi.y = g.w;
      *(float2*)&xf[c][sg << 2] = glo;
      *(float2*)&xf[c][(sg << 2) + 2] = ghi;
      ssq0 = fmaf(g.x, g.x, ssq0); ssq1 = fmaf(g.y, g.y, ssq1);
      ssq2 = fmaf(g.z, g.z, ssq2); ssq3 = fmaf(g.w, g.w, ssq3);
      float4 gw = *(const float4*)&w[(c << 9) + c0 + (sg << 2)];  // w[k=c][c0+4sg]
      short4v hw; hw.x = f2bf(gw.x); hw.y = f2bf(gw.y); hw.z = f2bf(gw.z); hw.w = f2bf(gw.w);
      *(short4v*)&wb[c][sg << 2] = hw;
    }
    __syncthreads();
#pragma unroll
    for (int cc = 0; cc < 64; cc += 32) {
      bf16x8 af = *(const bf16x8*)&wb[(wid << 4) + col][cc + (quad << 3)];
      int cb = cc + (quad << 3);
#pragma unroll
      for (int sgr = 0; sgr < 4; ++sgr) {
        int sc = (sgr << 4) + col;
        bf16x8 bfr;
#pragma unroll
        for (int j = 0; j < 8; ++j) bfr[j] = f2bf(xf[cb + j][sc]);  // 2-way (free)
        acc[sgr] = __builtin_amdgcn_mfma_f32_16x16x32_bf16(af, bfr, acc[sgr], 0, 0, 0);
      }
    }
    __syncthreads();
  }

  // ---- per-s inverse norm (thread's 4 s fixed = 4sg..4sg+3) ----
  ssq0 += __shfl_xor(ssq0, 16, 64); ssq0 += __shfl_xor(ssq0, 32, 64);
  ssq1 += __shfl_xor(ssq1, 16, 64); ssq1 += __shfl_xor(ssq1, 32, 64);
  ssq2 += __shfl_xor(ssq2, 16, 64); ssq2 += __shfl_xor(ssq2, 32, 64);
  ssq3 += __shfl_xor(ssq3, 16, 64); ssq3 += __shfl_xor(ssq3, 32, 64);
  if (lane < 16) {
    float4 v; v.x = ssq0; v.y = ssq1; v.z = ssq2; v.w = ssq3;
    *(float4*)&red[wid][sg << 2] = v;
  }
  __syncthreads();
  if (t < 64) {
    float tot = red[0][t] + red[1][t] + red[2][t] + red[3][t];
    invs[t] = 1.0f / fmaxf(sqrtf(tot), EPSF);
  }
  __syncthreads();

  // ---- softmax over k for each s ----
  float li[4];
#pragma unroll
  for (int sgr = 0; sgr < 4; ++sgr) li[sgr] = invs[(sgr << 4) + col];
  float le[4][4];
#pragma unroll
  for (int sgr = 0; sgr < 4; ++sgr)
#pragma unroll
    for (int r = 0; r < 4; ++r) le[sgr][r] = acc[sgr][r] * li[sgr];

  float mx[4];
#pragma unroll
  for (int sgr = 0; sgr < 4; ++sgr) {
    float m = fmaxf(fmaxf(le[sgr][0], le[sgr][1]), fmaxf(le[sgr][2], le[sgr][3]));
    m = fmaxf(m, __shfl_xor(m, 16, 64));
    m = fmaxf(m, __shfl_xor(m, 32, 64));
    mx[sgr] = m;
  }
  if (lane < 16) {
#pragma unroll
    for (int sgr = 0; sgr < 4; ++sgr) red[wid][(sgr << 4) + sg] = mx[sgr];
  }
  __syncthreads();
  if (t < 64)
    gmaxs[t] = fmaxf(fmaxf(red[0][t], red[1][t]), fmaxf(red[2][t], red[3][t]));
  __syncthreads();

  float ps[4];
#pragma unroll
  for (int sgr = 0; sgr < 4; ++sgr) {
    float gm = gmaxs[(sgr << 4) + col];
    float p = 0.f;
#pragma unroll
    for (int r = 0; r < 4; ++r) {
      float e = __expf(le[sgr][r] - gm);
      le[sgr][r] = e;
      p += e;
    }
    p += __shfl_xor(p, 16, 64);
    p += __shfl_xor(p, 32, 64);
    ps[sgr] = p;
  }
  if (lane < 16) {
#pragma unroll
    for (int sgr = 0; sgr < 4; ++sgr) red[wid][(sgr << 4) + sg] = ps[sgr];
  }
  __syncthreads();
  if (t < 64) gsums[t] = red[0][t] + red[1][t] + red[2][t] + red[3][t];
  __syncthreads();

  // ---- a, a' = a*invn, suma ----
  float sk[4] = {0.f, 0.f, 0.f, 0.f};
#pragma unroll
  for (int sgr = 0; sgr < 4; ++sgr) {
    float rinv = 1.0f / gsums[(sgr << 4) + col];
#pragma unroll
    for (int r = 0; r < 4; ++r) {
      float av = le[sgr][r] * rinv;            // a
      sk[r] += av;
      float apv = av * li[sgr];                // a' = a*invn[s]
      int k = (wid << 4) + (quad << 2) + r;
      ap[((size_t)((n << 6) + k) << 10) + s0 + (sgr << 4) + col] =
          (unsigned short)f2bf(apv);
    }
  }
#pragma unroll
  for (int r = 0; r < 4; ++r) {
    sk[r] += __shfl_xor(sk[r], 1, 64);
    sk[r] += __shfl_xor(sk[r], 2, 64);
    sk[r] += __shfl_xor(sk[r], 4, 64);
    sk[r] += __shfl_xor(sk[r], 8, 64);
  }
  if (col == 0) {
#pragma unroll
    for (int r = 0; r < 4; ++r)
      atomicAdd(&suma[(n << 6) + (wid << 4) + (quad << 2) + r], sk[r]);
  }
}

// K3: vlad^T[c,k] = sum_s x[c,s]*a'[k,s]  (bf16 MFMA, x as A, a' as B),
// then - suma[k]*cent[k,c], rnorm2 atomics, LDS-transposed coalesced store.
// R6 restructure (occupancy + barrier-drain):
//  (1) c-split: 32-c tiles, grid (64 n, 16 c0t) = 1024 blocks = 4 blocks/CU
//      (was 2 — grid-limited). s-reduction stays in-block: no combine pass,
//      no extra traffic. wg id = n + 64*c0t keeps ap[n] XCD-local.
//  (2) LDS double-buffer -> ONE __syncthreads per 64-s tile (was 2). Each
//      barrier drains vmcnt(0) (m97 structural stall); halving barrier count
//      + 2x blocks/CU covers the exposed HBM latency.
//  Wave w: c-band cb=(w&1)*16, k-band kb=(w>>1)*32; acc = 2 f32x4.
#define K3_LOADT(GX0, GX1, GA0, GA1, TI)                                       \
  do {                                                                         \
    const int so_ = (TI) << 6;                                                 \
    GX0 = *(const float4*)(xbase + so_);                                       \
    GX1 = *(const float4*)(xbase + so_ + 32);                                  \
    GA0 = *(const bf16x8*)(abase + so_);                                       \
    GA1 = *(const bf16x8*)(abase + so_ + 32);                                  \
  } while (0)

#define K3_WRITET(GX0, GX1, GA0, GA1, XB, AT)                                  \
  do {                                                                         \
    short4v h0, h1;                                                            \
    h0.x = f2bf(GX0.x); h0.y = f2bf(GX0.y); h0.z = f2bf(GX0.z); h0.w = f2bf(GX0.w); \
    h1.x = f2bf(GX1.x); h1.y = f2bf(GX1.y); h1.z = f2bf(GX1.z); h1.w = f2bf(GX1.w); \
    *(short4v*)&XB[t >> 3][(t & 7) << 2] = h0;                                 \
    *(short4v*)&XB[t >> 3][((t & 7) << 2) + 32] = h1;                          \
    *(bf16x8*)&AT[t >> 2][(t & 3) << 3] = GA0;                                 \
    *(bf16x8*)&AT[t >> 2][((t & 3) << 3) + 32] = GA1;                          \
  } while (0)

#define K3_MFMAT(XB, AT)                                                       \
  do {                                                                         \
    _Pragma("unroll") for (int ss = 0; ss < 64; ss += 32) {                    \
      bf16x8 af = *(const bf16x8*)&XB[cb + col][ss + (quad << 3)];             \
      _Pragma("unroll") for (int kt = 0; kt < 2; ++kt) {                       \
        bf16x8 bfr = *(const bf16x8*)&AT[kb + (kt << 4) + col][ss + (quad << 3)]; \
        acc[kt] = __builtin_amdgcn_mfma_f32_16x16x32_bf16(af, bfr, acc[kt], 0, 0, 0); \
      }                                                                        \
    }                                                                          \
  } while (0)

__global__ __launch_bounds__(256, 4) void k3_mfma(
    const float* __restrict__ x, const unsigned short* __restrict__ ap,
    const float* __restrict__ cent, const float* __restrict__ suma,
    float* __restrict__ out, float* __restrict__ rnorm2) {
  // buf0: xb0@0 (32x72 bf16), at0@4608 (64x72 bf16); buf1 @13824/@18432.
  // lt (64k x 36c fp32, 9216 B) aliases buf0 in the epilogue.
  __shared__ __align__(16) char sm[27648];
  short (*xb0)[72] = reinterpret_cast<short(*)[72]>(sm);
  short (*at0)[72] = reinterpret_cast<short(*)[72]>(sm + 4608);
  short (*xb1)[72] = reinterpret_cast<short(*)[72]>(sm + 13824);
  short (*at1)[72] = reinterpret_cast<short(*)[72]>(sm + 18432);
  float (*lt)[36] = reinterpret_cast<float(*)[36]>(sm);

  const int n = blockIdx.x;            // wg id % 8 == n % 8 -> XCD-local ap
  const int c0 = blockIdx.y << 5;      // 32-c tile
  const int t = threadIdx.x;
  const int lane = t & 63;
  const int wid = t >> 6;
  const int col = t & 15;
  const int quad = (t >> 4) & 3;
  const int sg = t & 15;
  const int cb = (wid & 1) << 4;       // c-band 0/16
  const int kb = (wid >> 1) << 5;      // k-band 0/32

  f32x4 acc[2] = {{0, 0, 0, 0}, {0, 0, 0, 0}};

  // staging bases: x rows t>>3 (32 rows, 8 thr/row, 2 float4 each);
  // ap rows t>>2 (64 rows, 4 thr/row, 2 bf16x8 each)
  const float* xbase = &x[((size_t)((n << 9) + c0 + (t >> 3)) << 10) + ((t & 7) << 2)];
  const unsigned short* abase = &ap[((size_t)((n << 6) + (t >> 2)) << 10) + ((t & 3) << 3)];

  float4 xA0, xA1, xB0, xB1;
  bf16x8 aA0, aA1, aB0, aB1;

  K3_LOADT(xA0, xA1, aA0, aA1, 0);
  K3_WRITET(xA0, xA1, aA0, aA1, xb0, at0);   // tile 0 -> buf0
  K3_LOADT(xB0, xB1, aB0, aB1, 1);           // issue tile 1
  __syncthreads();

#pragma unroll 1
  for (int it = 0; it < 16; it += 2) {
    const bool last = (it == 14);
    K3_WRITET(xB0, xB1, aB0, aB1, xb1, at1);            // tile it+1 -> buf1
    if (!last) K3_LOADT(xA0, xA1, aA0, aA1, it + 2);    // issue it+2 early
    K3_MFMAT(xb0, at0);                                 // compute tile it
    __syncthreads();
    if (!last) {
      K3_WRITET(xA0, xA1, aA0, aA1, xb0, at0);          // tile it+2 -> buf0
      K3_LOADT(xB0, xB1, aB0, aB1, it + 3);             // issue it+3 early
    }
    K3_MFMAT(xb1, at1);                                 // compute tile it+1
    __syncthreads();
  }

  // epilogue: lane holds D[c = cb+quad*4+r][k = kb+kt*16+col]
  const float sa0 = suma[(n << 6) + kb + col];
  const float sa1 = suma[(n << 6) + kb + 16 + col];
  const int crow = cb + (quad << 2);
  const int k0 = kb + col;
  const int k1 = kb + 16 + col;
  float r2_0 = 0.f, r2_1 = 0.f;
#pragma unroll
  for (int r = 0; r < 4; ++r) {
    int c = crow + r;
    float ce0 = cent[(k0 << 9) + c0 + c];
    float v0 = acc[0][r] - sa0 * ce0;
    r2_0 = fmaf(v0, v0, r2_0);
    lt[k0][c] = v0;
    float ce1 = cent[(k1 << 9) + c0 + c];
    float v1 = acc[1][r] - sa1 * ce1;
    r2_1 = fmaf(v1, v1, r2_1);
    lt[k1][c] = v1;
  }
  r2_0 += __shfl_xor(r2_0, 16, 64); r2_0 += __shfl_xor(r2_0, 32, 64);
  r2_1 += __shfl_xor(r2_1, 16, 64); r2_1 += __shfl_xor(r2_1, 32, 64);
  if (lane < 16) {
    atomicAdd(&rnorm2[(n << 6) + kb + sg], r2_0);
    atomicAdd(&rnorm2[(n << 6) + kb + 16 + sg], r2_1);
  }
  __syncthreads();
  // coalesced store of the 64k x 32c tile (4 thr/row, 2 float4 each)
#pragma unroll
  for (int u = 0; u < 2; ++u) {
    int kk = t >> 2;
    int c = ((t & 3) << 2) + (u << 4);
    float4 v = *(const float4*)&lt[kk][c];
    *(float4*)&out[((size_t)((n << 6) + kk) << 9) + c0 + c] = v;
  }
}

// K5 (absorbs former K4): per block (1024 consecutive floats = one n,
// two k-rows), wave 0 recomputes the per-n global-norm factor from rnorm2
// (64 floats, L2-hot) and broadcasts via LDS; then in-place scale.
__global__ __launch_bounds__(256) void k5_scale(const float* __restrict__ vlad,
                                                const float* __restrict__ rnorm2,
                                                float* __restrict__ out) {
  __shared__ float gsh;
  const int b = blockIdx.x;
  const int t = threadIdx.x;
  const int n = b >> 5;                 // 32 blocks per n
  if (t < 64) {                          // wave 0 only
    float rn = sqrtf(rnorm2[(n << 6) + t]);
    float nr = rn / fmaxf(rn, EPSF);
    float g = nr * nr;
#pragma unroll
    for (int off = 32; off > 0; off >>= 1) g += __shfl_xor(g, off, 64);
    if (t == 0) gsh = g;
  }
  __syncthreads();
  const float ginv = 1.0f / fmaxf(sqrtf(gsh), EPSF);
  const int idx = (b << 8) + t;          // float4 index
  const int kg = idx >> 7;               // = n*64 + k  (512 floats per k-row)
  float rn = sqrtf(rnorm2[kg]);
  float f = (1.0f / fmaxf(rn, EPSF)) * ginv;
  float4 v = ((const float4*)vlad)[idx];
  float4 o;
  o.x = v.x * f; o.y = v.y * f; o.z = v.z * f; o.w = v.w * f;
  ((float4*)out)[idx] = o;
}

extern "C" void kernel_launch(void* const* d_in, const int* in_sizes, int n_in,
                              void* d_out, int out_size, void* d_ws, size_t ws_size,
                              hipStream_t stream) {
  (void)in_sizes; (void)n_in; (void)out_size; (void)ws_size;
  const float* x = (const float*)d_in[0];     // (64,512,32,32)
  const float* w = (const float*)d_in[1];     // (64,512)
  const float* cent = (const float*)d_in[2];  // (64,512)
  float* out = (float*)d_out;                 // (64, 64*512)

  float* ws = (float*)d_ws;
  float* suma = ws;                                   // 4096
  float* rnorm2 = ws + 4096;                          // 4096
  unsigned short* ap = (unsigned short*)(ws + 12288); // 64*64*1024 bf16 = 8 MB

  hipMemsetAsync(ws, 0, 8192 * sizeof(float), stream);  // suma + rnorm2
  k2_mfma<<<dim3(16, 64), 256, 0, stream>>>(x, w, ap, suma);
  k3_mfma<<<dim3(64, 16), 256, 0, stream>>>(x, ap, cent, suma, out, rnorm2);
  k5_scale<<<2048, 256, 0, stream>>>(out, rnorm2, out);
}

// Round 3
// 227.622 us; speedup vs baseline: 1.1379x; 1.0028x over previous
//
#include <hip/hip_runtime.h>
#include <hip/hip_bf16.h>
#include <math.h>

#define EPSF 1e-12f

typedef __attribute__((ext_vector_type(8))) short bf16x8;
typedef __attribute__((ext_vector_type(4))) float f32x4;
typedef __attribute__((ext_vector_type(16))) float f32x16;
typedef __attribute__((ext_vector_type(4))) short short4v;
typedef __attribute__((ext_vector_type(4))) unsigned short ushort4v;

static __device__ __forceinline__ short f2bf(float f) {
  union { __hip_bfloat16 h; short s; } u;
  u.h = __float2bfloat16(f);
  return u.s;
}

// K2: logits = (w @ x) * invn[s]  via bf16 MFMA; fused per-s L2-norm;
// softmax over k; writes a' = a*invn (bf16) and suma (fp32 atomics).
// R7: MFMA shape 16x16x32 -> 32x32x16. The B-fragment (x, K=c is the
// non-contiguous dim -> per-element LDS gather) now covers 32 s-cols x 16 c,
// halving the gather+cvt glue: 64 -> 32 ds_read_b32 + cvt per wave per
// c-chunk, MFMA count 16 -> 4 (at the faster 32x32 rate). Gather banks:
// lanes 0-31 span 32 consecutive s -> 32 banks; lanes 32-63 read c+8 ->
// bank+16 -> 2-way only (free, m136).
// Wave w: kband=(w&1)*32, sband=(w>>1)*32. acc f32x16, C/D mapping
// col=lane&31, row=(reg&3)+8*(reg>>2)+4*(lane>>5) (m74/m101).
// NOTE (R4 post-mortem): in-LDS transpose of x regressed k2 35->92 us
// (3rd barrier/tile + conflicted transpose reads). Keep the gather.
__global__ __launch_bounds__(256) void k2_mfma(
    const float* __restrict__ x, const float* __restrict__ w,
    unsigned short* __restrict__ ap, float* __restrict__ suma) {
  __shared__ __align__(16) float xf[64][70];   // [c_local][s_local] fp32
  __shared__ __align__(16) short wb[64][72];   // [k][c_local] bf16
  __shared__ __align__(16) float red[4][64];   // per-wave reduction scratch
  __shared__ float invs[64];
  __shared__ float gmaxs[64];
  __shared__ float gsums[64];

  const int n = blockIdx.y;
  const int s0 = blockIdx.x << 6;
  const int t = threadIdx.x;
  const int lane = t & 63;
  const int wid = t >> 6;
  const int l31 = t & 31;
  const int half = lane >> 5;          // 0/1 -> K-group / +4 on acc row
  const int kband = (wid & 1) << 5;    // 0/32
  const int sband = (wid >> 1) << 5;   // 0/32
  const int cr = t >> 4;               // staging row 0..15
  const int sg = t & 15;               // staging float4 col

  f32x16 acc = {0,0,0,0,0,0,0,0,0,0,0,0,0,0,0,0};
  float ssq0 = 0.f, ssq1 = 0.f, ssq2 = 0.f, ssq3 = 0.f;

  for (int c0 = 0; c0 < 512; c0 += 64) {
#pragma unroll
    for (int p = 0; p < 4; ++p) {
      int c = cr + (p << 4);
      float4 g = *(const float4*)&x[((size_t)((n << 9) + c0 + c) << 10) + s0 + (sg << 2)];
      float2 glo; glo.x = g.x; glo.y = g.y;
      float2 ghi; ghi.x = g.z; ghi.y = g.w;
      *(float2*)&xf[c][sg << 2] = glo;
      *(float2*)&xf[c][(sg << 2) + 2] = ghi;
      ssq0 = fmaf(g.x, g.x, ssq0); ssq1 = fmaf(g.y, g.y, ssq1);
      ssq2 = fmaf(g.z, g.z, ssq2); ssq3 = fmaf(g.w, g.w, ssq3);
      float4 gw = *(const float4*)&w[(c << 9) + c0 + (sg << 2)];  // w[k=c][c0+4sg]
      short4v hw; hw.x = f2bf(gw.x); hw.y = f2bf(gw.y); hw.z = f2bf(gw.z); hw.w = f2bf(gw.w);
      *(short4v*)&wb[c][sg << 2] = hw;
    }
    __syncthreads();
#pragma unroll
    for (int ks = 0; ks < 4; ++ks) {
      const int cb = (ks << 4) + (half << 3);   // K-elems c = cb..cb+7
      bf16x8 af = *(const bf16x8*)&wb[kband + l31][cb];
      bf16x8 bfr;
#pragma unroll
      for (int j = 0; j < 8; ++j) bfr[j] = f2bf(xf[cb + j][sband + l31]);
      acc = __builtin_amdgcn_mfma_f32_32x32x16_bf16(af, bfr, acc, 0, 0, 0);
    }
    __syncthreads();
  }

  // ---- per-s inverse norm (thread's 4 s fixed = 4sg..4sg+3) ----
  ssq0 += __shfl_xor(ssq0, 16, 64); ssq0 += __shfl_xor(ssq0, 32, 64);
  ssq1 += __shfl_xor(ssq1, 16, 64); ssq1 += __shfl_xor(ssq1, 32, 64);
  ssq2 += __shfl_xor(ssq2, 16, 64); ssq2 += __shfl_xor(ssq2, 32, 64);
  ssq3 += __shfl_xor(ssq3, 16, 64); ssq3 += __shfl_xor(ssq3, 32, 64);
  if (lane < 16) {
    float4 v; v.x = ssq0; v.y = ssq1; v.z = ssq2; v.w = ssq3;
    *(float4*)&red[wid][sg << 2] = v;
  }
  __syncthreads();
  if (t < 64) {
    float tot = red[0][t] + red[1][t] + red[2][t] + red[3][t];
    invs[t] = 1.0f / fmaxf(sqrtf(tot), EPSF);
  }
  __syncthreads();

  // ---- softmax over k for each s (lane's s is fixed = sband + l31) ----
  const int sl = sband + l31;
  const float li = invs[sl];
  float le[16];
#pragma unroll
  for (int r = 0; r < 16; ++r) le[r] = acc[r] * li;

  float m = le[0];
#pragma unroll
  for (int r = 1; r < 16; ++r) m = fmaxf(m, le[r]);
  m = fmaxf(m, __shfl_xor(m, 32, 64));     // other kband-half within wave
  if (lane < 32) red[wid][l31] = m;
  __syncthreads();
  if (t < 64) {
    int w0 = (t >> 5) << 1;                // waves {w0, w0+1} share sband t>>5
    gmaxs[t] = fmaxf(red[w0][t & 31], red[w0 + 1][t & 31]);
  }
  __syncthreads();

  const float gm = gmaxs[sl];
  float p = 0.f;
#pragma unroll
  for (int r = 0; r < 16; ++r) {
    float e = __expf(le[r] - gm);
    le[r] = e;
    p += e;
  }
  p += __shfl_xor(p, 32, 64);
  if (lane < 32) red[wid][l31] = p;
  __syncthreads();
  if (t < 64) {
    int w0 = (t >> 5) << 1;
    gsums[t] = red[w0][t & 31] + red[w0 + 1][t & 31];
  }
  __syncthreads();

  // ---- a, a' = a*invn, suma ----
  const float rinv = 1.0f / gsums[sl];
  const int kb2 = kband + (half << 2);
#pragma unroll
  for (int r = 0; r < 16; ++r) {
    float av = le[r] * rinv;               // a
    le[r] = av;
    float apv = av * li;                   // a' = a*invn[s]
    int k = kb2 + (r & 3) + ((r >> 2) << 3);
    ap[((size_t)((n << 6) + k) << 10) + s0 + sl] = (unsigned short)f2bf(apv);
  }
#pragma unroll
  for (int r = 0; r < 16; ++r) {
    float v = le[r];
    v += __shfl_xor(v, 1, 64);
    v += __shfl_xor(v, 2, 64);
    v += __shfl_xor(v, 4, 64);
    v += __shfl_xor(v, 8, 64);
    v += __shfl_xor(v, 16, 64);
    if (l31 == 0) {
      int k = kb2 + (r & 3) + ((r >> 2) << 3);
      atomicAdd(&suma[(n << 6) + k], v);
    }
  }
}

// K3: vlad^T[c,k] = sum_s x[c,s]*a'[k,s]  (bf16 MFMA, x as A, a' as B),
// then - suma[k]*cent[k,c], rnorm2 atomics, LDS-transposed coalesced store.
// R6 restructure (occupancy + barrier-drain):
//  (1) c-split: 32-c tiles, grid (64 n, 16 c0t) = 1024 blocks = 4 blocks/CU
//      (was 2 — grid-limited). s-reduction stays in-block: no combine pass,
//      no extra traffic. wg id = n + 64*c0t keeps ap[n] XCD-local.
//  (2) LDS double-buffer -> ONE __syncthreads per 64-s tile (was 2).
//  R2 post-mortem: this restructure was NEUTRAL (k3 was already near floor;
//  its x re-read is likely L3-served). Kept — no churn.
//  Wave w: c-band cb=(w&1)*16, k-band kb=(w>>1)*32; acc = 2 f32x4.
#define K3_LOADT(GX0, GX1, GA0, GA1, TI)                                       \
  do {                                                                         \
    const int so_ = (TI) << 6;                                                 \
    GX0 = *(const float4*)(xbase + so_);                                       \
    GX1 = *(const float4*)(xbase + so_ + 32);                                  \
    GA0 = *(const bf16x8*)(abase + so_);                                       \
    GA1 = *(const bf16x8*)(abase + so_ + 32);                                  \
  } while (0)

#define K3_WRITET(GX0, GX1, GA0, GA1, XB, AT)                                  \
  do {                                                                         \
    short4v h0, h1;                                                            \
    h0.x = f2bf(GX0.x); h0.y = f2bf(GX0.y); h0.z = f2bf(GX0.z); h0.w = f2bf(GX0.w); \
    h1.x = f2bf(GX1.x); h1.y = f2bf(GX1.y); h1.z = f2bf(GX1.z); h1.w = f2bf(GX1.w); \
    *(short4v*)&XB[t >> 3][(t & 7) << 2] = h0;                                 \
    *(short4v*)&XB[t >> 3][((t & 7) << 2) + 32] = h1;                          \
    *(bf16x8*)&AT[t >> 2][(t & 3) << 3] = GA0;                                 \
    *(bf16x8*)&AT[t >> 2][((t & 3) << 3) + 32] = GA1;                          \
  } while (0)

#define K3_MFMAT(XB, AT)                                                       \
  do {                                                                         \
    _Pragma("unroll") for (int ss = 0; ss < 64; ss += 32) {                    \
      bf16x8 af = *(const bf16x8*)&XB[cb + col][ss + (quad << 3)];             \
      _Pragma("unroll") for (int kt = 0; kt < 2; ++kt) {                       \
        bf16x8 bfr = *(const bf16x8*)&AT[kb + (kt << 4) + col][ss + (quad << 3)]; \
        acc[kt] = __builtin_amdgcn_mfma_f32_16x16x32_bf16(af, bfr, acc[kt], 0, 0, 0); \
      }                                                                        \
    }                                                                          \
  } while (0)

__global__ __launch_bounds__(256, 4) void k3_mfma(
    const float* __restrict__ x, const unsigned short* __restrict__ ap,
    const float* __restrict__ cent, const float* __restrict__ suma,
    float* __restrict__ out, float* __restrict__ rnorm2) {
  // buf0: xb0@0 (32x72 bf16), at0@4608 (64x72 bf16); buf1 @13824/@18432.
  // lt (64k x 36c fp32, 9216 B) aliases buf0 in the epilogue.
  __shared__ __align__(16) char sm[27648];
  short (*xb0)[72] = reinterpret_cast<short(*)[72]>(sm);
  short (*at0)[72] = reinterpret_cast<short(*)[72]>(sm + 4608);
  short (*xb1)[72] = reinterpret_cast<short(*)[72]>(sm + 13824);
  short (*at1)[72] = reinterpret_cast<short(*)[72]>(sm + 18432);
  float (*lt)[36] = reinterpret_cast<float(*)[36]>(sm);

  const int n = blockIdx.x;            // wg id % 8 == n % 8 -> XCD-local ap
  const int c0 = blockIdx.y << 5;      // 32-c tile
  const int t = threadIdx.x;
  const int lane = t & 63;
  const int wid = t >> 6;
  const int col = t & 15;
  const int quad = (t >> 4) & 3;
  const int sg = t & 15;
  const int cb = (wid & 1) << 4;       // c-band 0/16
  const int kb = (wid >> 1) << 5;      // k-band 0/32

  f32x4 acc[2] = {{0, 0, 0, 0}, {0, 0, 0, 0}};

  // staging bases: x rows t>>3 (32 rows, 8 thr/row, 2 float4 each);
  // ap rows t>>2 (64 rows, 4 thr/row, 2 bf16x8 each)
  const float* xbase = &x[((size_t)((n << 9) + c0 + (t >> 3)) << 10) + ((t & 7) << 2)];
  const unsigned short* abase = &ap[((size_t)((n << 6) + (t >> 2)) << 10) + ((t & 3) << 3)];

  float4 xA0, xA1, xB0, xB1;
  bf16x8 aA0, aA1, aB0, aB1;

  K3_LOADT(xA0, xA1, aA0, aA1, 0);
  K3_WRITET(xA0, xA1, aA0, aA1, xb0, at0);   // tile 0 -> buf0
  K3_LOADT(xB0, xB1, aB0, aB1, 1);           // issue tile 1
  __syncthreads();

#pragma unroll 1
  for (int it = 0; it < 16; it += 2) {
    const bool last = (it == 14);
    K3_WRITET(xB0, xB1, aB0, aB1, xb1, at1);            // tile it+1 -> buf1
    if (!last) K3_LOADT(xA0, xA1, aA0, aA1, it + 2);    // issue it+2 early
    K3_MFMAT(xb0, at0);                                 // compute tile it
    __syncthreads();
    if (!last) {
      K3_WRITET(xA0, xA1, aA0, aA1, xb0, at0);          // tile it+2 -> buf0
      K3_LOADT(xB0, xB1, aB0, aB1, it + 3);             // issue it+3 early
    }
    K3_MFMAT(xb1, at1);                                 // compute tile it+1
    __syncthreads();
  }

  // epilogue: lane holds D[c = cb+quad*4+r][k = kb+kt*16+col]
  const float sa0 = suma[(n << 6) + kb + col];
  const float sa1 = suma[(n << 6) + kb + 16 + col];
  const int crow = cb + (quad << 2);
  const int k0 = kb + col;
  const int k1 = kb + 16 + col;
  float r2_0 = 0.f, r2_1 = 0.f;
#pragma unroll
  for (int r = 0; r < 4; ++r) {
    int c = crow + r;
    float ce0 = cent[(k0 << 9) + c0 + c];
    float v0 = acc[0][r] - sa0 * ce0;
    r2_0 = fmaf(v0, v0, r2_0);
    lt[k0][c] = v0;
    float ce1 = cent[(k1 << 9) + c0 + c];
    float v1 = acc[1][r] - sa1 * ce1;
    r2_1 = fmaf(v1, v1, r2_1);
    lt[k1][c] = v1;
  }
  r2_0 += __shfl_xor(r2_0, 16, 64); r2_0 += __shfl_xor(r2_0, 32, 64);
  r2_1 += __shfl_xor(r2_1, 16, 64); r2_1 += __shfl_xor(r2_1, 32, 64);
  if (lane < 16) {
    atomicAdd(&rnorm2[(n << 6) + kb + sg], r2_0);
    atomicAdd(&rnorm2[(n << 6) + kb + 16 + sg], r2_1);
  }
  __syncthreads();
  // coalesced store of the 64k x 32c tile (4 thr/row, 2 float4 each)
#pragma unroll
  for (int u = 0; u < 2; ++u) {
    int kk = t >> 2;
    int c = ((t & 3) << 2) + (u << 4);
    float4 v = *(const float4*)&lt[kk][c];
    *(float4*)&out[((size_t)((n << 6) + kk) << 9) + c0 + c] = v;
  }
}

// K5 (absorbs former K4): per block (1024 consecutive floats = one n,
// two k-rows), wave 0 recomputes the per-n global-norm factor from rnorm2
// (64 floats, L2-hot) and broadcasts via LDS; then in-place scale.
__global__ __launch_bounds__(256) void k5_scale(const float* __restrict__ vlad,
                                                const float* __restrict__ rnorm2,
                                                float* __restrict__ out) {
  __shared__ float gsh;
  const int b = blockIdx.x;
  const int t = threadIdx.x;
  const int n = b >> 5;                 // 32 blocks per n
  if (t < 64) {                          // wave 0 only
    float rn = sqrtf(rnorm2[(n << 6) + t]);
    float nr = rn / fmaxf(rn, EPSF);
    float g = nr * nr;
#pragma unroll
    for (int off = 32; off > 0; off >>= 1) g += __shfl_xor(g, off, 64);
    if (t == 0) gsh = g;
  }
  __syncthreads();
  const float ginv = 1.0f / fmaxf(sqrtf(gsh), EPSF);
  const int idx = (b << 8) + t;          // float4 index
  const int kg = idx >> 7;               // = n*64 + k  (512 floats per k-row)
  float rn = sqrtf(rnorm2[kg]);
  float f = (1.0f / fmaxf(rn, EPSF)) * ginv;
  float4 v = ((const float4*)vlad)[idx];
  float4 o;
  o.x = v.x * f; o.y = v.y * f; o.z = v.z * f; o.w = v.w * f;
  ((float4*)out)[idx] = o;
}

extern "C" void kernel_launch(void* const* d_in, const int* in_sizes, int n_in,
                              void* d_out, int out_size, void* d_ws, size_t ws_size,
                              hipStream_t stream) {
  (void)in_sizes; (void)n_in; (void)out_size; (void)ws_size;
  const float* x = (const float*)d_in[0];     // (64,512,32,32)
  const float* w = (const float*)d_in[1];     // (64,512)
  const float* cent = (const float*)d_in[2];  // (64,512)
  float* out = (float*)d_out;                 // (64, 64*512)

  float* ws = (float*)d_ws;
  float* suma = ws;                                   // 4096
  float* rnorm2 = ws + 4096;                          // 4096
  unsigned short* ap = (unsigned short*)(ws + 12288); // 64*64*1024 bf16 = 8 MB

  hipMemsetAsync(ws, 0, 8192 * sizeof(float), stream);  // suma + rnorm2
  k2_mfma<<<dim3(16, 64), 256, 0, stream>>>(x, w, ap, suma);
  k3_mfma<<<dim3(64, 16), 256, 0, stream>>>(x, ap, cent, suma, out, rnorm2);
  k5_scale<<<2048, 256, 0, stream>>>(out, rnorm2, out);
}